// Round 5
// baseline (77731.628 us; speedup 1.0000x reference)
//
#include <hip/hip_runtime.h>

#define EPSF 1e-5f

typedef unsigned short u16;
typedef unsigned int u32;

__device__ __forceinline__ u16 f2bf(float f) {
  u32 u = __float_as_uint(f);
  u += 0x7fffu + ((u >> 16) & 1u);   // RNE
  return (u16)(u >> 16);
}
__device__ __forceinline__ u32 packbf(float lo, float hi) {
  return (u32)f2bf(lo) | ((u32)f2bf(hi) << 16);
}

#if __has_builtin(__builtin_amdgcn_fdot2_f32_bf16)
typedef __attribute__((ext_vector_type(2))) __bf16 bf16x2;
__device__ __forceinline__ float dot2bf(u32 w, u32 h, float acc) {
  union { u32 u; bf16x2 v; } a, b; a.u = w; b.u = h;
  return __builtin_amdgcn_fdot2_f32_bf16(a.v, b.v, acc, false);
}
#else
__device__ __forceinline__ float dot2bf(u32 w, u32 h, float acc) {
  float r = fmaf(__uint_as_float(w << 16), __uint_as_float(h << 16), acc);
  return fmaf(__uint_as_float(w & 0xffff0000u), __uint_as_float(h & 0xffff0000u), r);
}
#endif

__global__ void init_flags(u32* flags) {
  flags[blockIdx.x * blockDim.x + threadIdx.x] = 0;   // 2048 u32
}

// grid 256: block = (r = bid&63, s = bid>>6). 512 threads.
// WG owns W1 rows [s*256, s*256+256) in VGPRs, W2 rows [s*128, s*128+128) in LDS.
__global__ __launch_bounds__(512, 2)
void rnn_kernel(const float* __restrict__ xs, const float* __restrict__ h0,
                const float* __restrict__ gamma, const float* __restrict__ beta,
                const float* __restrict__ W1f,
                const float* __restrict__ lnh_w, const float* __restrict__ lnh_b,
                const float* __restrict__ W2f,
                const float* __restrict__ lnx_w, const float* __restrict__ lnx_b,
                float* __restrict__ out,
                float* __restrict__ hh_ex, float* __restrict__ y_ex,
                u32* __restrict__ flags) {
  const int bid = blockIdx.x;
  const int r = bid & 63, s = bid >> 6;
  const int tid = threadIdx.x;
  const int w = tid >> 6, lane = tid & 63;
  const int N = 512;

  __shared__ __align__(16) uint4 W2s4[8192];       // 128 KB bf16-packed W2 slice
  __shared__ __align__(16) float out_t[32][128];   // 16 KB
  __shared__ u32 hb2[256], xb2[256];
  __shared__ float red_s[8], red_q[8];

  // ---- W1 slice -> VGPRs (static-indexed array, no spill) ----
  const int jloc = w * 32 + (lane & 31);
  const int j = s * 256 + jloc;
  const int khalf = lane >> 5;
  uint4 wv1[32];
  {
    const float4* w1row = (const float4*)(W1f + (size_t)j * 512) + khalf * 64;
    #pragma unroll
    for (int c = 0; c < 32; ++c) {
      float4 a = w1row[c * 2], b = w1row[c * 2 + 1];
      wv1[c].x = packbf(a.x, a.y); wv1[c].y = packbf(a.z, a.w);
      wv1[c].z = packbf(b.x, b.y); wv1[c].w = packbf(b.z, b.w);
    }
  }
  // ---- W2 slice -> LDS (bank-swizzled: nl ^ (kq<<1)) ----
  for (int e = 0; e < 16; ++e) {
    int idx = e * 512 + tid;                 // 0..8191 = kqc*128 + nl_store
    int kqc = idx >> 7;                      // kq*16 + c
    int nl = (idx & 127) ^ ((idx >> 11) << 1);
    int n = s * 128 + nl;
    int kb = (kqc >> 4) * 128 + (kqc & 15) * 8;
    const float4* w2p = (const float4*)(W2f + (size_t)n * 512 + kb);
    float4 a = w2p[0], b = w2p[1];
    uint4 u;
    u.x = packbf(a.x, a.y); u.y = packbf(a.z, a.w);
    u.z = packbf(b.x, b.y); u.w = packbf(b.z, b.w);
    W2s4[idx] = u;
  }

  // ---- per-thread params (n = tid) ----
  const float w1w_i = lnh_w[tid], w1b_i = lnh_b[tid];
  const float w1w_g = lnh_w[512 + tid], w1b_g = lnh_b[512 + tid];
  const float g0 = gamma[0 * N + tid], g1 = gamma[1 * N + tid], g2 = gamma[2 * N + tid];
  const float b0 = beta[0 * N + tid],  b1 = beta[1 * N + tid],  b2 = beta[2 * N + tid];
  const float w2w = lnx_w[tid], w2b = lnx_b[tid];
  float h_v = h0[(size_t)r * N + tid];
  {
    float hnb = __shfl_down(h_v, 1);
    if (!(tid & 1)) hb2[tid >> 1] = packbf(h_v, hnb);
  }
  u32* flagA = flags + r * 16;
  u32* flagB = flags + 1024 + r * 16;
  float* hh_r = hh_ex + (size_t)r * 1024;
  float* y_r  = y_ex + (size_t)r * 512;
  const float* xs_b = xs + (size_t)r * 3 * N * 1024;
  const int kq = lane >> 4;
  const int nl2 = w * 16 + (lane & 15);
  const uint4* w2base = W2s4 + kq * 2048 + ((nl2 & 127) ^ (kq << 1));
  __syncthreads();

  for (int t0 = 0; t0 < 1024; t0 += 4) {
    float4 xr0 = *(const float4*)(xs_b + (size_t)(0 * N + tid) * 1024 + t0);
    float4 xr1 = *(const float4*)(xs_b + (size_t)(1 * N + tid) * 1024 + t0);
    float4 xr2 = *(const float4*)(xs_b + (size_t)(2 * N + tid) * 1024 + t0);
    #pragma unroll
    for (int q = 0; q < 4; ++q) {
      const int t = t0 + q;
      const int tt = t & 31;

      // ---- in_layer (regs) ----
      float s0 = 1.f / (1.f + __expf(-(g0 * h_v + b0)));
      float s1 = 1.f / (1.f + __expf(-(g1 * h_v + b1)));
      float s2 = 1.f / (1.f + __expf(-(g2 * h_v + b2)));
      float x0 = (q == 0) ? xr0.x : (q == 1) ? xr0.y : (q == 2) ? xr0.z : xr0.w;
      float x1 = (q == 0) ? xr1.x : (q == 1) ? xr1.y : (q == 2) ? xr1.z : xr1.w;
      float x2 = (q == 0) ? xr2.x : (q == 1) ? xr2.y : (q == 2) ? xr2.z : xr2.w;
      float il = fmaxf(s0 * x0 + s1 * x1 + s2 * x2, 0.f);

      // ---- mm1 slice: VGPR weights x LDS-broadcast h ----
      const uint4* hp4 = ((const uint4*)hb2) + khalf * 32;
      float a0 = 0.f, a1 = 0.f, a2 = 0.f, a3 = 0.f;
      #pragma unroll
      for (int c = 0; c < 32; ++c) {
        uint4 h4 = hp4[c];
        a0 = dot2bf(wv1[c].x, h4.x, a0); a1 = dot2bf(wv1[c].y, h4.y, a1);
        a2 = dot2bf(wv1[c].z, h4.z, a2); a3 = dot2bf(wv1[c].w, h4.w, a3);
      }
      float acc = (a0 + a1) + (a2 + a3);
      float full = acc + __shfl_xor(acc, 32);
      if (lane < 32) hh_r[s * 256 + jloc] = full;
      __threadfence();
      __syncthreads();
      if (tid == 0) {
        __hip_atomic_fetch_add(flagA, 1u, __ATOMIC_RELEASE, __HIP_MEMORY_SCOPE_AGENT);
        u32 tgt = 4u * (u32)t + 4u;
        while (__hip_atomic_load(flagA, __ATOMIC_ACQUIRE, __HIP_MEMORY_SCOPE_AGENT) < tgt)
          __builtin_amdgcn_s_sleep(1);
      }
      __syncthreads();

      // ---- read full hh, LN1 stats (redundant, identical in all WGs) ----
      float v0 = __hip_atomic_load(&hh_r[tid], __ATOMIC_RELAXED, __HIP_MEMORY_SCOPE_AGENT);
      float v1 = __hip_atomic_load(&hh_r[512 + tid], __ATOMIC_RELAXED, __HIP_MEMORY_SCOPE_AGENT);
      {
        float ssum = v0 + v1, sq = v0 * v0 + v1 * v1;
        #pragma unroll
        for (int off = 32; off > 0; off >>= 1) {
          ssum += __shfl_down(ssum, off); sq += __shfl_down(sq, off);
        }
        if (lane == 0) { red_s[w] = ssum; red_q[w] = sq; }
      }
      __syncthreads();
      float S = red_s[tid & 7], Q = red_q[tid & 7];
      #pragma unroll
      for (int off = 4; off > 0; off >>= 1) {
        S += __shfl_xor(S, off); Q += __shfl_xor(Q, off);
      }
      float mu1 = S * (1.f / 1024.f);
      float rinv1 = rsqrtf(Q * (1.f / 1024.f) - mu1 * mu1 + EPSF);

      float x_v = fmaxf(il + (v0 - mu1) * rinv1 * w1w_i + w1b_i, 0.f);
      float hg_n = (v1 - mu1) * rinv1 * w1w_g + w1b_g;
      {
        float xnb = __shfl_down(x_v, 1);
        if (!(tid & 1)) xb2[tid >> 1] = packbf(x_v, xnb);
      }
      __syncthreads();

      // ---- mm2 slice: LDS weights x LDS-broadcast x ----
      const uint4* xp4 = ((const uint4*)xb2) + kq * 16;
      float c0 = 0.f, c1 = 0.f, c2 = 0.f, c3 = 0.f;
      #pragma unroll
      for (int c = 0; c < 16; ++c) {
        uint4 wv = w2base[c * 128];
        uint4 x4 = xp4[c];
        c0 = dot2bf(wv.x, x4.x, c0); c1 = dot2bf(wv.y, x4.y, c1);
        c2 = dot2bf(wv.z, x4.z, c2); c3 = dot2bf(wv.w, x4.w, c3);
      }
      float yp = (c0 + c1) + (c2 + c3);
      yp += __shfl_xor(yp, 16);
      yp += __shfl_xor(yp, 32);
      if (lane < 16) y_r[s * 128 + nl2] = yp;
      __threadfence();
      __syncthreads();
      if (tid == 0) {
        __hip_atomic_fetch_add(flagB, 1u, __ATOMIC_RELEASE, __HIP_MEMORY_SCOPE_AGENT);
        u32 tgt = 4u * (u32)t + 4u;
        while (__hip_atomic_load(flagB, __ATOMIC_ACQUIRE, __HIP_MEMORY_SCOPE_AGENT) < tgt)
          __builtin_amdgcn_s_sleep(1);
      }
      __syncthreads();

      // ---- read full y, LN2 stats, gate, state update ----
      float yv = __hip_atomic_load(&y_r[tid], __ATOMIC_RELAXED, __HIP_MEMORY_SCOPE_AGENT);
      {
        float ssum = yv, sq = yv * yv;
        #pragma unroll
        for (int off = 32; off > 0; off >>= 1) {
          ssum += __shfl_down(ssum, off); sq += __shfl_down(sq, off);
        }
        if (lane == 0) { red_s[w] = ssum; red_q[w] = sq; }
      }
      __syncthreads();
      float S2 = red_s[tid & 7], Q2 = red_q[tid & 7];
      #pragma unroll
      for (int off = 4; off > 0; off >>= 1) {
        S2 += __shfl_xor(S2, off); Q2 += __shfl_xor(Q2, off);
      }
      float mu2 = S2 * (1.f / 512.f);
      float rinv2 = rsqrtf(Q2 * (1.f / 512.f) - mu2 * mu2 + EPSF);

      float yn = (yv - mu2) * rinv2 * w2w + w2b;
      float gg = 1.f / (1.f + __expf(-(yn + hg_n)));
      float hn = h_v + gg * (x_v - h_v);
      h_v = hn;
      if ((tid >> 7) == s) out_t[tt][tid & 127] = hn;
      {
        float hnb = __shfl_down(hn, 1);
        if (!(tid & 1)) hb2[tid >> 1] = packbf(hn, hnb);
      }
      __syncthreads();

      // ---- flush this WG's n-slice every 32 steps ----
      if (tt == 31) {
        const int n_l = tid >> 2;
        const int seg = tid & 3;
        float* op = out + ((size_t)r * N + s * 128 + n_l) * 1024 + (t - 31) + seg * 8;
        #pragma unroll
        for (int i = 0; i < 2; ++i) {
          float4 v;
          v.x = out_t[seg * 8 + i * 4 + 0][n_l];
          v.y = out_t[seg * 8 + i * 4 + 1][n_l];
          v.z = out_t[seg * 8 + i * 4 + 2][n_l];
          v.w = out_t[seg * 8 + i * 4 + 3][n_l];
          *(float4*)(op + i * 4) = v;
        }
      }
    }
  }
}

extern "C" void kernel_launch(void* const* d_in, const int* in_sizes, int n_in,
                              void* d_out, int out_size, void* d_ws, size_t ws_size,
                              hipStream_t stream) {
  const float* xs    = (const float*)d_in[0];
  const float* h0    = (const float*)d_in[1];
  const float* gamma = (const float*)d_in[2];
  const float* beta  = (const float*)d_in[3];
  const float* W1    = (const float*)d_in[4];
  const float* lnh_w = (const float*)d_in[5];
  const float* lnh_b = (const float*)d_in[6];
  const float* W2    = (const float*)d_in[7];
  const float* lnx_w = (const float*)d_in[8];
  const float* lnx_b = (const float*)d_in[9];
  float* out = (float*)d_out;

  float* hh_ex = (float*)d_ws;                       // 64*1024 f32 = 256 KB
  float* y_ex  = hh_ex + 64 * 1024;                  // 64*512 f32 = 128 KB
  u32*   flags = (u32*)(y_ex + 64 * 512);            // 2048 u32 = 8 KB

  init_flags<<<8, 256, 0, stream>>>(flags);
  rnn_kernel<<<256, 512, 0, stream>>>(xs, h0, gamma, beta, W1,
                                      lnh_w, lnh_b, W2, lnx_w, lnx_b, out,
                                      hh_ex, y_ex, flags);
}

// Round 6
// 51841.718 us; speedup vs baseline: 1.4994x; 1.4994x over previous
//
#include <hip/hip_runtime.h>

#define EPSF 1e-5f

typedef unsigned short u16;
typedef unsigned int u32;

__device__ __forceinline__ u16 f2bf(float f) {
  u32 u = __float_as_uint(f);
  u += 0x7fffu + ((u >> 16) & 1u);   // RNE
  return (u16)(u >> 16);
}
__device__ __forceinline__ u32 packbf(float lo, float hi) {
  return (u32)f2bf(lo) | ((u32)f2bf(hi) << 16);
}

#if __has_builtin(__builtin_amdgcn_fdot2_f32_bf16)
typedef __attribute__((ext_vector_type(2))) __bf16 bf16x2;
__device__ __forceinline__ float dot2bf(u32 w, u32 h, float acc) {
  union { u32 u; bf16x2 v; } a, b; a.u = w; b.u = h;
  return __builtin_amdgcn_fdot2_f32_bf16(a.v, b.v, acc, false);
}
#else
__device__ __forceinline__ float dot2bf(u32 w, u32 h, float acc) {
  float r = fmaf(__uint_as_float(w << 16), __uint_as_float(h << 16), acc);
  return fmaf(__uint_as_float(w & 0xffff0000u), __uint_as_float(h & 0xffff0000u), r);
}
#endif

// W1p: u16 idx (kk*1024 + j)*8 + r = bf16(W1[j][kk*8+r]), kk 0..63 (lane-coalesced 16B)
// W2p: u16 idx (kk*512  + n)*8 + r = bf16(W2[n][kk*8+r]), kk 0..63
__global__ void prep_weights(const float* __restrict__ W1, const float* __restrict__ W2,
                             u16* __restrict__ W1p, u16* __restrict__ W2p) {
  int i = blockIdx.x * blockDim.x + threadIdx.x;
  if (i < 1024 * 64) {
    int j = i >> 6, kk = i & 63;
    const float* src = W1 + (size_t)j * 512 + kk * 8;
    u16* dst = W1p + ((size_t)(kk * 1024 + j)) * 8;
    #pragma unroll
    for (int r = 0; r < 8; ++r) dst[r] = f2bf(src[r]);
  }
  if (i < 512 * 64) {
    int n = i >> 6, kk = i & 63;
    const float* src = W2 + (size_t)n * 512 + kk * 8;
    u16* dst = W2p + ((size_t)(kk * 512 + n)) * 8;
    #pragma unroll
    for (int r = 0; r < 8; ++r) dst[r] = f2bf(src[r]);
  }
}

// 64 blocks (one per batch row) x 512 threads. Thread tid owns:
//   mm1 outputs j = tid (i-half) and j = tid+512 (g-half), mm2 output n = tid.
__global__ __launch_bounds__(512, 2)
void rnn_kernel(const float* __restrict__ xs, const float* __restrict__ h0,
                const float* __restrict__ gamma, const float* __restrict__ beta,
                const u16* __restrict__ W1p,
                const float* __restrict__ lnh_w, const float* __restrict__ lnh_b,
                const u16* __restrict__ W2p,
                const float* __restrict__ lnx_w, const float* __restrict__ lnx_b,
                float* __restrict__ out) {
  const int r = blockIdx.x;
  const int tid = threadIdx.x;
  const int w = tid >> 6, lane = tid & 63;
  const int N = 512;

  __shared__ u32 hb2[256];
  __shared__ u32 xb2[256];
  __shared__ float red_s[8], red_q[8];
  __shared__ __align__(16) float out_t[32][512];   // 64 KB, conflict-free both ways

  // per-thread params
  const float w1w_i = lnh_w[tid],       w1b_i = lnh_b[tid];
  const float w1w_g = lnh_w[512 + tid], w1b_g = lnh_b[512 + tid];
  const float g0 = gamma[0 * N + tid], g1 = gamma[1 * N + tid], g2 = gamma[2 * N + tid];
  const float b0 = beta[0 * N + tid],  b1 = beta[1 * N + tid],  b2 = beta[2 * N + tid];
  const float w2w = lnx_w[tid], w2b = lnx_b[tid];

  float h_v = h0[(size_t)r * N + tid];
  {
    float hnb = __shfl_down(h_v, 1);
    if (!(tid & 1)) hb2[tid >> 1] = packbf(h_v, hnb);
  }
  const float* xs_b = xs + (size_t)r * 3 * N * 1024;
  const uint4* wpa = ((const uint4*)W1p) + tid;          // elem kk at [kk*1024]
  const uint4* wpb = ((const uint4*)W1p) + tid + 512;
  const uint4* wp2 = ((const uint4*)W2p) + tid;          // elem kk at [kk*512]
  __syncthreads();

  for (int t0 = 0; t0 < 1024; t0 += 4) {
    float4 xr0 = *(const float4*)(xs_b + (size_t)(0 * N + tid) * 1024 + t0);
    float4 xr1 = *(const float4*)(xs_b + (size_t)(1 * N + tid) * 1024 + t0);
    float4 xr2 = *(const float4*)(xs_b + (size_t)(2 * N + tid) * 1024 + t0);
    #pragma unroll
    for (int q = 0; q < 4; ++q) {
      const int t = t0 + q;
      const int tt = t & 31;

      // ---- in_layer (regs) ----
      float il;
      {
        float s0 = 1.f / (1.f + __expf(-(g0 * h_v + b0)));
        float s1 = 1.f / (1.f + __expf(-(g1 * h_v + b1)));
        float s2 = 1.f / (1.f + __expf(-(g2 * h_v + b2)));
        float x0 = (q == 0) ? xr0.x : (q == 1) ? xr0.y : (q == 2) ? xr0.z : xr0.w;
        float x1 = (q == 0) ? xr1.x : (q == 1) ? xr1.y : (q == 2) ? xr1.z : xr1.w;
        float x2 = (q == 0) ? xr2.x : (q == 1) ? xr2.y : (q == 2) ? xr2.z : xr2.w;
        il = fmaxf(s0 * x0 + s1 * x1 + s2 * x2, 0.f);
      }

      // ---- mm1: two j-streams, double-buffered depth-16 pipeline ----
      float acc_i, acc_g;
      {
        const uint4* hp4 = (const uint4*)hb2;     // wave-uniform broadcast
        uint4 Aa[8], Ab[8], Ba[8], Bb[8];
        #pragma unroll
        for (int u = 0; u < 8; ++u) { Aa[u] = wpa[u * 1024]; Ab[u] = wpb[u * 1024]; }
        float i0 = 0, i1 = 0, i2 = 0, i3 = 0;
        float e0 = 0, e1 = 0, e2 = 0, e3 = 0;
        #pragma unroll
        for (int c = 0; c < 7; ++c) {
          #pragma unroll
          for (int u = 0; u < 8; ++u) {
            Ba[u] = wpa[((c + 1) * 8 + u) * 1024];
            Bb[u] = wpb[((c + 1) * 8 + u) * 1024];
          }
          #pragma unroll
          for (int u = 0; u < 8; ++u) {
            uint4 h4 = hp4[c * 8 + u];
            i0 = dot2bf(Aa[u].x, h4.x, i0); i1 = dot2bf(Aa[u].y, h4.y, i1);
            i2 = dot2bf(Aa[u].z, h4.z, i2); i3 = dot2bf(Aa[u].w, h4.w, i3);
            e0 = dot2bf(Ab[u].x, h4.x, e0); e1 = dot2bf(Ab[u].y, h4.y, e1);
            e2 = dot2bf(Ab[u].z, h4.z, e2); e3 = dot2bf(Ab[u].w, h4.w, e3);
          }
          #pragma unroll
          for (int u = 0; u < 8; ++u) { Aa[u] = Ba[u]; Ab[u] = Bb[u]; }
        }
        #pragma unroll
        for (int u = 0; u < 8; ++u) {
          uint4 h4 = hp4[56 + u];
          i0 = dot2bf(Aa[u].x, h4.x, i0); i1 = dot2bf(Aa[u].y, h4.y, i1);
          i2 = dot2bf(Aa[u].z, h4.z, i2); i3 = dot2bf(Aa[u].w, h4.w, i3);
          e0 = dot2bf(Ab[u].x, h4.x, e0); e1 = dot2bf(Ab[u].y, h4.y, e1);
          e2 = dot2bf(Ab[u].z, h4.z, e2); e3 = dot2bf(Ab[u].w, h4.w, e3);
        }
        acc_i = (i0 + i1) + (i2 + i3);
        acc_g = (e0 + e1) + (e2 + e3);
      }

      // ---- LN1 stats over 1024 (both halves per thread) ----
      {
        float s = acc_i + acc_g, qq = acc_i * acc_i + acc_g * acc_g;
        #pragma unroll
        for (int off = 32; off > 0; off >>= 1) {
          s += __shfl_down(s, off); qq += __shfl_down(qq, off);
        }
        if (lane == 0) { red_s[w] = s; red_q[w] = qq; }
      }
      __syncthreads();                                   // B1
      float mu1, rinv1;
      {
        float s = red_s[tid & 7], qq = red_q[tid & 7];
        #pragma unroll
        for (int off = 4; off > 0; off >>= 1) {
          s += __shfl_xor(s, off); qq += __shfl_xor(qq, off);
        }
        mu1 = s * (1.f / 1024.f);
        rinv1 = rsqrtf(qq * (1.f / 1024.f) - mu1 * mu1 + EPSF);
      }

      // ---- LN1 apply: x (reg + packed LDS) and h_g (stays in reg) ----
      float x_v = fmaxf(il + (acc_i - mu1) * rinv1 * w1w_i + w1b_i, 0.f);
      float hg_n = (acc_g - mu1) * rinv1 * w1w_g + w1b_g;
      {
        float xnb = __shfl_down(x_v, 1);
        if (!(tid & 1)) xb2[tid >> 1] = packbf(x_v, xnb);
      }
      __syncthreads();                                   // B2

      // ---- mm2: one n-stream, double-buffered depth-8 ----
      float accf;
      {
        const uint4* xp4 = (const uint4*)xb2;
        uint4 A[8], B[8];
        #pragma unroll
        for (int u = 0; u < 8; ++u) A[u] = wp2[u * 512];
        float c0 = 0, c1 = 0, c2 = 0, c3 = 0;
        #pragma unroll
        for (int c = 0; c < 7; ++c) {
          #pragma unroll
          for (int u = 0; u < 8; ++u) B[u] = wp2[((c + 1) * 8 + u) * 512];
          #pragma unroll
          for (int u = 0; u < 8; ++u) {
            uint4 x4 = xp4[c * 8 + u];
            c0 = dot2bf(A[u].x, x4.x, c0); c1 = dot2bf(A[u].y, x4.y, c1);
            c2 = dot2bf(A[u].z, x4.z, c2); c3 = dot2bf(A[u].w, x4.w, c3);
          }
          #pragma unroll
          for (int u = 0; u < 8; ++u) A[u] = B[u];
        }
        #pragma unroll
        for (int u = 0; u < 8; ++u) {
          uint4 x4 = xp4[56 + u];
          c0 = dot2bf(A[u].x, x4.x, c0); c1 = dot2bf(A[u].y, x4.y, c1);
          c2 = dot2bf(A[u].z, x4.z, c2); c3 = dot2bf(A[u].w, x4.w, c3);
        }
        accf = (c0 + c1) + (c2 + c3);
      }

      // ---- LN2 stats over 512 ----
      {
        float s = accf, qq = accf * accf;
        #pragma unroll
        for (int off = 32; off > 0; off >>= 1) {
          s += __shfl_down(s, off); qq += __shfl_down(qq, off);
        }
        if (lane == 0) { red_s[w] = s; red_q[w] = qq; }
      }
      __syncthreads();                                   // B3
      {
        float s = red_s[tid & 7], qq = red_q[tid & 7];
        #pragma unroll
        for (int off = 4; off > 0; off >>= 1) {
          s += __shfl_xor(s, off); qq += __shfl_xor(qq, off);
        }
        float mu2 = s * (1.f / 512.f);
        float rinv2 = rsqrtf(qq * (1.f / 512.f) - mu2 * mu2 + EPSF);

        // ---- gate + state update ----
        float y = (accf - mu2) * rinv2 * w2w + w2b;
        float gg = 1.f / (1.f + __expf(-(y + hg_n)));
        float hn = h_v + gg * (x_v - h_v);
        out_t[tt][tid] = hn;
        h_v = hn;
        float hnb = __shfl_down(hn, 1);
        if (!(tid & 1)) hb2[tid >> 1] = packbf(hn, hnb);
      }
      __syncthreads();                                   // B4

      // ---- flush every 32 steps: thread tid owns row n=tid (no cross-thread dep) ----
      if (tt == 31) {
        float* op = out + ((size_t)r * N + tid) * 1024 + (t - 31);
        #pragma unroll
        for (int i = 0; i < 8; ++i) {
          float4 v;
          v.x = out_t[i * 4 + 0][tid];
          v.y = out_t[i * 4 + 1][tid];
          v.z = out_t[i * 4 + 2][tid];
          v.w = out_t[i * 4 + 3][tid];
          *(float4*)(op + i * 4) = v;
        }
      }
    }
  }
}

extern "C" void kernel_launch(void* const* d_in, const int* in_sizes, int n_in,
                              void* d_out, int out_size, void* d_ws, size_t ws_size,
                              hipStream_t stream) {
  const float* xs    = (const float*)d_in[0];
  const float* h0    = (const float*)d_in[1];
  const float* gamma = (const float*)d_in[2];
  const float* beta  = (const float*)d_in[3];
  const float* W1    = (const float*)d_in[4];
  const float* lnh_w = (const float*)d_in[5];
  const float* lnh_b = (const float*)d_in[6];
  const float* W2    = (const float*)d_in[7];
  const float* lnx_w = (const float*)d_in[8];
  const float* lnx_b = (const float*)d_in[9];
  float* out = (float*)d_out;

  u16* W1p = (u16*)d_ws;                    // 1 MB
  u16* W2p = W1p + (size_t)1024 * 512;      // 0.5 MB

  prep_weights<<<(65536 + 255) / 256, 256, 0, stream>>>(W1, W2, W1p, W2p);
  rnn_kernel<<<64, 512, 0, stream>>>(xs, h0, gamma, beta, W1p,
                                     lnh_w, lnh_b, W2p, lnx_w, lnx_b, out);
}

// Round 7
// 49099.197 us; speedup vs baseline: 1.5832x; 1.0559x over previous
//
#include <hip/hip_runtime.h>

#define EPSF 1e-5f

typedef unsigned short u16;
typedef unsigned int u32;

__device__ __forceinline__ u16 f2bf(float f) {
  u32 u = __float_as_uint(f);
  u += 0x7fffu + ((u >> 16) & 1u);   // RNE
  return (u16)(u >> 16);
}
__device__ __forceinline__ u32 packbf(float lo, float hi) {
  return (u32)f2bf(lo) | ((u32)f2bf(hi) << 16);
}

#if __has_builtin(__builtin_amdgcn_fdot2_f32_bf16)
typedef __attribute__((ext_vector_type(2))) __bf16 bf16x2;
__device__ __forceinline__ float dot2bf(u32 w, u32 h, float acc) {
  union { u32 u; bf16x2 v; } a, b; a.u = w; b.u = h;
  return __builtin_amdgcn_fdot2_f32_bf16(a.v, b.v, acc, false);
}
#else
__device__ __forceinline__ float dot2bf(u32 w, u32 h, float acc) {
  float r = fmaf(__uint_as_float(w << 16), __uint_as_float(h << 16), acc);
  return fmaf(__uint_as_float(w & 0xffff0000u), __uint_as_float(h & 0xffff0000u), r);
}
#endif

// W1p: u16 idx (kk*1024 + j)*8 + r = bf16(W1[j][kk*8+r]), kk 0..63 (lane-coalesced 16B)
// W2p: u16 idx (kk*512  + n)*8 + r = bf16(W2[n][kk*8+r]), kk 0..63
__global__ void prep_weights(const float* __restrict__ W1, const float* __restrict__ W2,
                             u16* __restrict__ W1p, u16* __restrict__ W2p) {
  int i = blockIdx.x * blockDim.x + threadIdx.x;
  if (i < 1024 * 64) {
    int j = i >> 6, kk = i & 63;
    const float* src = W1 + (size_t)j * 512 + kk * 8;
    u16* dst = W1p + ((size_t)(kk * 1024 + j)) * 8;
    #pragma unroll
    for (int r = 0; r < 8; ++r) dst[r] = f2bf(src[r]);
  }
  if (i < 512 * 64) {
    int n = i >> 6, kk = i & 63;
    const float* src = W2 + (size_t)n * 512 + kk * 8;
    u16* dst = W2p + ((size_t)(kk * 512 + n)) * 8;
    #pragma unroll
    for (int r = 0; r < 8; ++r) dst[r] = f2bf(src[r]);
  }
}

// 64 blocks (one per batch row) x 512 threads, 1 block/CU -> 256-VGPR budget.
// Thread tid owns mm1 outputs j=tid and j=tid+512, and mm2 output n=tid.
__global__ __launch_bounds__(512, 1)
void rnn_kernel(const float* __restrict__ xs, const float* __restrict__ h0,
                const float* __restrict__ gamma, const float* __restrict__ beta,
                const u16* __restrict__ W1p,
                const float* __restrict__ lnh_w, const float* __restrict__ lnh_b,
                const u16* __restrict__ W2p,
                const float* __restrict__ lnx_w, const float* __restrict__ lnx_b,
                float* __restrict__ out) {
  const int r = blockIdx.x;
  const int tid = threadIdx.x;
  const int w = tid >> 6, lane = tid & 63;
  const int N = 512;

  __shared__ u32 hb2[256];
  __shared__ u32 xb2[256];
  __shared__ float red_s[8], red_q[8];
  __shared__ __align__(16) float out_t[32][512];   // 64 KB

  const float w1w_i = lnh_w[tid],       w1b_i = lnh_b[tid];
  const float w1w_g = lnh_w[512 + tid], w1b_g = lnh_b[512 + tid];
  const float g0 = gamma[0 * N + tid], g1 = gamma[1 * N + tid], g2 = gamma[2 * N + tid];
  const float b0 = beta[0 * N + tid],  b1 = beta[1 * N + tid],  b2 = beta[2 * N + tid];
  const float w2w = lnx_w[tid], w2b = lnx_b[tid];

  float h_v = h0[(size_t)r * N + tid];
  {
    float hnb = __shfl_down(h_v, 1);
    if (!(tid & 1)) hb2[tid >> 1] = packbf(h_v, hnb);
  }
  const float* xs_b = xs + (size_t)r * 3 * N * 1024;
  const uint4* wpa = ((const uint4*)W1p) + tid;          // elem kk at [kk*1024]
  const uint4* wpb = ((const uint4*)W1p) + tid + 512;
  const uint4* wp2 = ((const uint4*)W2p) + tid;          // elem kk at [kk*512]
  __syncthreads();

#define MM1_LOAD(DA, DB, c1)                                   \
  _Pragma("unroll") for (int u = 0; u < 8; ++u) {              \
    DA[u] = wpa[((c1) * 8 + u) * 1024];                        \
    DB[u] = wpb[((c1) * 8 + u) * 1024];                        \
  }
#define MM1_COMP(SA, SB, c)                                    \
  _Pragma("unroll") for (int u = 0; u < 8; ++u) {              \
    uint4 h4 = hp4[(c) * 8 + u];                               \
    i0 = dot2bf(SA[u].x, h4.x, i0); i1 = dot2bf(SA[u].y, h4.y, i1); \
    i2 = dot2bf(SA[u].z, h4.z, i2); i3 = dot2bf(SA[u].w, h4.w, i3); \
    e0 = dot2bf(SB[u].x, h4.x, e0); e1 = dot2bf(SB[u].y, h4.y, e1); \
    e2 = dot2bf(SB[u].z, h4.z, e2); e3 = dot2bf(SB[u].w, h4.w, e3); \
  }
#define MM2_LOAD(D, c1)                                        \
  _Pragma("unroll") for (int u = 0; u < 8; ++u) {              \
    D[u] = wp2[((c1) * 8 + u) * 512];                          \
  }
#define MM2_COMP(S, c)                                         \
  _Pragma("unroll") for (int u = 0; u < 8; ++u) {              \
    uint4 x4 = xp4[(c) * 8 + u];                               \
    c0 = dot2bf(S[u].x, x4.x, c0); c1r = dot2bf(S[u].y, x4.y, c1r); \
    c2 = dot2bf(S[u].z, x4.z, c2); c3 = dot2bf(S[u].w, x4.w, c3); \
  }

  for (int t0 = 0; t0 < 1024; t0 += 4) {
    float4 xr0 = *(const float4*)(xs_b + (size_t)(0 * N + tid) * 1024 + t0);
    float4 xr1 = *(const float4*)(xs_b + (size_t)(1 * N + tid) * 1024 + t0);
    float4 xr2 = *(const float4*)(xs_b + (size_t)(2 * N + tid) * 1024 + t0);
    #pragma unroll
    for (int q = 0; q < 4; ++q) {
      const int t = t0 + q;
      const int tt = t & 31;

      // ---- in_layer (regs) ----
      float il;
      {
        float s0 = 1.f / (1.f + __expf(-(g0 * h_v + b0)));
        float s1 = 1.f / (1.f + __expf(-(g1 * h_v + b1)));
        float s2 = 1.f / (1.f + __expf(-(g2 * h_v + b2)));
        float x0 = (q == 0) ? xr0.x : (q == 1) ? xr0.y : (q == 2) ? xr0.z : xr0.w;
        float x1 = (q == 0) ? xr1.x : (q == 1) ? xr1.y : (q == 2) ? xr1.z : xr1.w;
        float x2 = (q == 0) ? xr2.x : (q == 1) ? xr2.y : (q == 2) ? xr2.z : xr2.w;
        il = fmaxf(s0 * x0 + s1 * x1 + s2 * x2, 0.f);
      }

      // ---- mm1: two j-streams, ping-pong depth-8 pipeline ----
      float acc_i, acc_g;
      {
        const uint4* hp4 = (const uint4*)hb2;     // wave-uniform broadcast
        uint4 Aa[8], Ab[8], Ba[8], Bb[8];
        float i0 = 0, i1 = 0, i2 = 0, i3 = 0;
        float e0 = 0, e1 = 0, e2 = 0, e3 = 0;
        MM1_LOAD(Aa, Ab, 0);
        MM1_LOAD(Ba, Bb, 1); MM1_COMP(Aa, Ab, 0);
        MM1_LOAD(Aa, Ab, 2); MM1_COMP(Ba, Bb, 1);
        MM1_LOAD(Ba, Bb, 3); MM1_COMP(Aa, Ab, 2);
        MM1_LOAD(Aa, Ab, 4); MM1_COMP(Ba, Bb, 3);
        MM1_LOAD(Ba, Bb, 5); MM1_COMP(Aa, Ab, 4);
        MM1_LOAD(Aa, Ab, 6); MM1_COMP(Ba, Bb, 5);
        MM1_LOAD(Ba, Bb, 7); MM1_COMP(Aa, Ab, 6);
        MM1_COMP(Ba, Bb, 7);
        acc_i = (i0 + i1) + (i2 + i3);
        acc_g = (e0 + e1) + (e2 + e3);
      }

      // ---- LN1 stats over 1024 (both halves per thread) ----
      {
        float s = acc_i + acc_g, qq = acc_i * acc_i + acc_g * acc_g;
        #pragma unroll
        for (int off = 32; off > 0; off >>= 1) {
          s += __shfl_down(s, off); qq += __shfl_down(qq, off);
        }
        if (lane == 0) { red_s[w] = s; red_q[w] = qq; }
      }
      __syncthreads();                                   // B1
      float mu1, rinv1;
      {
        float s = red_s[tid & 7], qq = red_q[tid & 7];
        #pragma unroll
        for (int off = 4; off > 0; off >>= 1) {
          s += __shfl_xor(s, off); qq += __shfl_xor(qq, off);
        }
        mu1 = s * (1.f / 1024.f);
        rinv1 = rsqrtf(qq * (1.f / 1024.f) - mu1 * mu1 + EPSF);
      }

      // ---- LN1 apply ----
      float x_v = fmaxf(il + (acc_i - mu1) * rinv1 * w1w_i + w1b_i, 0.f);
      float hg_n = (acc_g - mu1) * rinv1 * w1w_g + w1b_g;
      {
        float xnb = __shfl_down(x_v, 1);
        if (!(tid & 1)) xb2[tid >> 1] = packbf(x_v, xnb);
      }
      __syncthreads();                                   // B2

      // ---- mm2: one n-stream, ping-pong depth-8 ----
      float accf;
      {
        const uint4* xp4 = (const uint4*)xb2;
        uint4 A2[8], B2[8];
        float c0 = 0, c1r = 0, c2 = 0, c3 = 0;
        MM2_LOAD(A2, 0);
        MM2_LOAD(B2, 1); MM2_COMP(A2, 0);
        MM2_LOAD(A2, 2); MM2_COMP(B2, 1);
        MM2_LOAD(B2, 3); MM2_COMP(A2, 2);
        MM2_LOAD(A2, 4); MM2_COMP(B2, 3);
        MM2_LOAD(B2, 5); MM2_COMP(A2, 4);
        MM2_LOAD(A2, 6); MM2_COMP(B2, 5);
        MM2_LOAD(B2, 7); MM2_COMP(A2, 6);
        MM2_COMP(B2, 7);
        accf = (c0 + c1r) + (c2 + c3);
      }

      // ---- LN2 stats over 512 ----
      {
        float s = accf, qq = accf * accf;
        #pragma unroll
        for (int off = 32; off > 0; off >>= 1) {
          s += __shfl_down(s, off); qq += __shfl_down(qq, off);
        }
        if (lane == 0) { red_s[w] = s; red_q[w] = qq; }
      }
      __syncthreads();                                   // B3
      {
        float s = red_s[tid & 7], qq = red_q[tid & 7];
        #pragma unroll
        for (int off = 4; off > 0; off >>= 1) {
          s += __shfl_xor(s, off); qq += __shfl_xor(qq, off);
        }
        float mu2 = s * (1.f / 512.f);
        float rinv2 = rsqrtf(qq * (1.f / 512.f) - mu2 * mu2 + EPSF);

        // ---- gate + state update ----
        float y = (accf - mu2) * rinv2 * w2w + w2b;
        float gg = 1.f / (1.f + __expf(-(y + hg_n)));
        float hn = h_v + gg * (x_v - h_v);
        out_t[tt][tid] = hn;
        h_v = hn;
        float hnb = __shfl_down(hn, 1);
        if (!(tid & 1)) hb2[tid >> 1] = packbf(hn, hnb);
      }
      __syncthreads();                                   // B4

      // ---- flush every 32 steps: thread tid owns row n=tid ----
      if (tt == 31) {
        float* op = out + ((size_t)r * N + tid) * 1024 + (t - 31);
        #pragma unroll
        for (int i = 0; i < 8; ++i) {
          float4 v;
          v.x = out_t[i * 4 + 0][tid];
          v.y = out_t[i * 4 + 1][tid];
          v.z = out_t[i * 4 + 2][tid];
          v.w = out_t[i * 4 + 3][tid];
          *(float4*)(op + i * 4) = v;
        }
      }
    }
  }
}

extern "C" void kernel_launch(void* const* d_in, const int* in_sizes, int n_in,
                              void* d_out, int out_size, void* d_ws, size_t ws_size,
                              hipStream_t stream) {
  const float* xs    = (const float*)d_in[0];
  const float* h0    = (const float*)d_in[1];
  const float* gamma = (const float*)d_in[2];
  const float* beta  = (const float*)d_in[3];
  const float* W1    = (const float*)d_in[4];
  const float* lnh_w = (const float*)d_in[5];
  const float* lnh_b = (const float*)d_in[6];
  const float* W2    = (const float*)d_in[7];
  const float* lnx_w = (const float*)d_in[8];
  const float* lnx_b = (const float*)d_in[9];
  float* out = (float*)d_out;

  u16* W1p = (u16*)d_ws;                    // 1 MB
  u16* W2p = W1p + (size_t)1024 * 512;      // 0.5 MB

  prep_weights<<<(65536 + 255) / 256, 256, 0, stream>>>(W1, W2, W1p, W2p);
  rnn_kernel<<<64, 512, 0, stream>>>(xs, h0, gamma, beta, W1p,
                                     lnh_w, lnh_b, W2p, lnx_w, lnx_b, out);
}

// Round 8
// 40038.141 us; speedup vs baseline: 1.9414x; 1.2263x over previous
//
#include <hip/hip_runtime.h>

#define EPSF 1e-5f

typedef unsigned short u16;
typedef unsigned int u32;

__device__ __forceinline__ u16 f2bf(float f) {
  u32 u = __float_as_uint(f);
  u += 0x7fffu + ((u >> 16) & 1u);   // RNE
  return (u16)(u >> 16);
}
__device__ __forceinline__ u32 packbf(float lo, float hi) {
  return (u32)f2bf(lo) | ((u32)f2bf(hi) << 16);
}

#if __has_builtin(__builtin_amdgcn_fdot2_f32_bf16)
typedef __attribute__((ext_vector_type(2))) __bf16 bf16x2;
__device__ __forceinline__ float dot2bf(u32 w, u32 h, float acc) {
  union { u32 u; bf16x2 v; } a, b; a.u = w; b.u = h;
  return __builtin_amdgcn_fdot2_f32_bf16(a.v, b.v, acc, false);
}
#else
__device__ __forceinline__ float dot2bf(u32 w, u32 h, float acc) {
  float r = fmaf(__uint_as_float(w << 16), __uint_as_float(h << 16), acc);
  return fmaf(__uint_as_float(w & 0xffff0000u), __uint_as_float(h & 0xffff0000u), r);
}
#endif

// W1p: u16 idx (kk*1024 + j)*8 + r = bf16(W1[j][kk*8+r]), kk 0..63 (lane-coalesced 16B)
// W2p: u16 idx (kk*512  + n)*8 + r = bf16(W2[n][kk*8+r]), kk 0..63
__global__ void prep_weights(const float* __restrict__ W1, const float* __restrict__ W2,
                             u16* __restrict__ W1p, u16* __restrict__ W2p) {
  int i = blockIdx.x * blockDim.x + threadIdx.x;
  if (i < 1024 * 64) {
    int j = i >> 6, kk = i & 63;
    const float* src = W1 + (size_t)j * 512 + kk * 8;
    u16* dst = W1p + ((size_t)(kk * 1024 + j)) * 8;
    #pragma unroll
    for (int r = 0; r < 8; ++r) dst[r] = f2bf(src[r]);
  }
  if (i < 512 * 64) {
    int n = i >> 6, kk = i & 63;
    const float* src = W2 + (size_t)n * 512 + kk * 8;
    u16* dst = W2p + ((size_t)(kk * 512 + n)) * 8;
    #pragma unroll
    for (int r = 0; r < 8; ++r) dst[r] = f2bf(src[r]);
  }
}

// 64 blocks (one per batch row) x 1024 threads (16 waves).
// mm1: thread tid owns output j = tid (0..1023).
// mm2: thread owns n = tid&511, k-half = tid>>9.
__global__ __launch_bounds__(1024)
void rnn_kernel(const float* __restrict__ xs, const float* __restrict__ h0,
                const float* __restrict__ gamma, const float* __restrict__ beta,
                const u16* __restrict__ W1p,
                const float* __restrict__ lnh_w, const float* __restrict__ lnh_b,
                const u16* __restrict__ W2p,
                const float* __restrict__ lnx_w, const float* __restrict__ lnx_b,
                float* __restrict__ out) {
  const int r = blockIdx.x;
  const int tid = threadIdx.x;
  const int w = tid >> 6, lane = tid & 63;
  const int N = 512;

  __shared__ u32 hb2[256];
  __shared__ u32 xb2[256];
  __shared__ float hg_s[512];
  __shared__ float p2[1024];
  __shared__ float red_s[16], red_q[16];
  __shared__ __align__(16) float out_t[32][512];   // 64 KB

  // per-thread params
  const float w1w = lnh_w[tid], w1b = lnh_b[tid];
  float g0 = 0, g1 = 0, g2 = 0, b0 = 0, b1 = 0, b2 = 0, w2w = 0, w2b = 0;
  float h_v = 0.f, x_v = 0.f, il = 0.f;
  if (tid < N) {
    g0 = gamma[0 * N + tid]; g1 = gamma[1 * N + tid]; g2 = gamma[2 * N + tid];
    b0 = beta[0 * N + tid];  b1 = beta[1 * N + tid];  b2 = beta[2 * N + tid];
    w2w = lnx_w[tid]; w2b = lnx_b[tid];
    h_v = h0[(size_t)r * N + tid];
    float hnb = __shfl_down(h_v, 1);
    if (!(tid & 1)) hb2[tid >> 1] = packbf(h_v, hnb);
  }
  const float* xs_b = xs + (size_t)r * 3 * N * 1024;
  const uint4* wp1 = ((const uint4*)W1p) + tid;          // elem kk at wp1[kk*1024]
  const int n2 = tid & 511, half = tid >> 9;
  const uint4* wp2 = ((const uint4*)W2p) + n2 + (size_t)half * 32 * 512;  // local kk at wp2[kk*512]
  __syncthreads();

#define M1L(D, g)                                              \
  _Pragma("unroll") for (int u = 0; u < 4; ++u) {              \
    D[u] = wp1[((g) * 4 + u) * 1024];                          \
  }
#define M1C(S, g)                                              \
  _Pragma("unroll") for (int u = 0; u < 4; ++u) {              \
    uint4 h4 = hp4[(g) * 4 + u];                               \
    a0 = dot2bf(S[u].x, h4.x, a0); a1 = dot2bf(S[u].y, h4.y, a1); \
    a2 = dot2bf(S[u].z, h4.z, a2); a3 = dot2bf(S[u].w, h4.w, a3); \
  }
#define M2L(D, g)                                              \
  _Pragma("unroll") for (int u = 0; u < 4; ++u) {              \
    D[u] = wp2[((g) * 4 + u) * 512];                           \
  }
#define M2C(S, g)                                              \
  _Pragma("unroll") for (int u = 0; u < 4; ++u) {              \
    uint4 x4 = xp4[(g) * 4 + u];                               \
    a0 = dot2bf(S[u].x, x4.x, a0); a1 = dot2bf(S[u].y, x4.y, a1); \
    a2 = dot2bf(S[u].z, x4.z, a2); a3 = dot2bf(S[u].w, x4.w, a3); \
  }

  for (int t0 = 0; t0 < 1024; t0 += 4) {
    float4 xr0, xr1, xr2;
    if (tid < N) {
      xr0 = *(const float4*)(xs_b + (size_t)(0 * N + tid) * 1024 + t0);
      xr1 = *(const float4*)(xs_b + (size_t)(1 * N + tid) * 1024 + t0);
      xr2 = *(const float4*)(xs_b + (size_t)(2 * N + tid) * 1024 + t0);
    }
    #pragma unroll
    for (int q = 0; q < 4; ++q) {
      const int t = t0 + q;
      const int tt = t & 31;

      // ---- in_layer (regs) ----
      if (tid < N) {
        float s0 = 1.f / (1.f + __expf(-(g0 * h_v + b0)));
        float s1 = 1.f / (1.f + __expf(-(g1 * h_v + b1)));
        float s2 = 1.f / (1.f + __expf(-(g2 * h_v + b2)));
        float x0 = (q == 0) ? xr0.x : (q == 1) ? xr0.y : (q == 2) ? xr0.z : xr0.w;
        float x1 = (q == 0) ? xr1.x : (q == 1) ? xr1.y : (q == 2) ? xr1.z : xr1.w;
        float x2 = (q == 0) ? xr2.x : (q == 1) ? xr2.y : (q == 2) ? xr2.z : xr2.w;
        il = fmaxf(s0 * x0 + s1 * x1 + s2 * x2, 0.f);
      }

      // ---- mm1: j=tid, depth-4 ping-pong over 16 groups ----
      float acc;
      {
        const uint4* hp4 = (const uint4*)hb2;      // wave-uniform broadcast
        uint4 A[4], B[4];
        float a0 = 0, a1 = 0, a2 = 0, a3 = 0;
        M1L(A, 0);
        M1L(B, 1);  M1C(A, 0);
        M1L(A, 2);  M1C(B, 1);
        M1L(B, 3);  M1C(A, 2);
        M1L(A, 4);  M1C(B, 3);
        M1L(B, 5);  M1C(A, 4);
        M1L(A, 6);  M1C(B, 5);
        M1L(B, 7);  M1C(A, 6);
        M1L(A, 8);  M1C(B, 7);
        M1L(B, 9);  M1C(A, 8);
        M1L(A, 10); M1C(B, 9);
        M1L(B, 11); M1C(A, 10);
        M1L(A, 12); M1C(B, 11);
        M1L(B, 13); M1C(A, 12);
        M1L(A, 14); M1C(B, 13);
        M1L(B, 15); M1C(A, 14);
        M1C(B, 15);
        acc = (a0 + a1) + (a2 + a3);
      }

      // ---- LN1 stats over 1024 ----
      {
        float s = acc, qq = acc * acc;
        #pragma unroll
        for (int off = 32; off > 0; off >>= 1) {
          s += __shfl_down(s, off); qq += __shfl_down(qq, off);
        }
        if (lane == 0) { red_s[w] = s; red_q[w] = qq; }
      }
      __syncthreads();                                   // B1
      float mu1, rinv1;
      {
        float s = red_s[tid & 15], qq = red_q[tid & 15];
        #pragma unroll
        for (int off = 8; off > 0; off >>= 1) {
          s += __shfl_xor(s, off); qq += __shfl_xor(qq, off);
        }
        mu1 = s * (1.f / 1024.f);
        rinv1 = rsqrtf(qq * (1.f / 1024.f) - mu1 * mu1 + EPSF);
      }

      // ---- LN1 apply ----
      {
        float hh = (acc - mu1) * rinv1 * w1w + w1b;
        if (tid < N) {
          x_v = fmaxf(il + hh, 0.f);
          float xnb = __shfl_down(x_v, 1);
          if (!(tid & 1)) xb2[tid >> 1] = packbf(x_v, xnb);
        } else {
          hg_s[tid - N] = hh;
        }
      }
      __syncthreads();                                   // B2

      // ---- mm2: n=tid&511, k-half split, depth-4 ping-pong over 8 groups ----
      {
        const uint4* xp4 = ((const uint4*)xb2) + half * 32;
        uint4 A[4], B[4];
        float a0 = 0, a1 = 0, a2 = 0, a3 = 0;
        M2L(A, 0);
        M2L(B, 1); M2C(A, 0);
        M2L(A, 2); M2C(B, 1);
        M2L(B, 3); M2C(A, 2);
        M2L(A, 4); M2C(B, 3);
        M2L(B, 5); M2C(A, 4);
        M2L(A, 6); M2C(B, 5);
        M2L(B, 7); M2C(A, 6);
        M2C(B, 7);
        p2[tid] = (a0 + a1) + (a2 + a3);
      }
      __syncthreads();                                   // B3

      // ---- LN2 stats over 512 ----
      float accf = 0.f;
      {
        float s = 0.f, qq = 0.f;
        if (tid < N) {
          accf = p2[tid] + p2[tid + 512];
          s = accf; qq = accf * accf;
        }
        #pragma unroll
        for (int off = 32; off > 0; off >>= 1) {
          s += __shfl_down(s, off); qq += __shfl_down(qq, off);
        }
        if (lane == 0) { red_s[w] = s; red_q[w] = qq; }
      }
      __syncthreads();                                   // B4
      {
        float s = red_s[tid & 15], qq = red_q[tid & 15];
        #pragma unroll
        for (int off = 8; off > 0; off >>= 1) {
          s += __shfl_xor(s, off); qq += __shfl_xor(qq, off);
        }
        float mu2 = s * (1.f / 512.f);
        float rinv2 = rsqrtf(qq * (1.f / 512.f) - mu2 * mu2 + EPSF);

        // ---- gate + state update ----
        if (tid < N) {
          float y = (accf - mu2) * rinv2 * w2w + w2b;
          float gg = 1.f / (1.f + __expf(-(y + hg_s[tid])));
          float hn = h_v + gg * (x_v - h_v);
          out_t[tt][tid] = hn;
          h_v = hn;
          float hnb = __shfl_down(hn, 1);
          if (!(tid & 1)) hb2[tid >> 1] = packbf(hn, hnb);
        }
      }
      __syncthreads();                                   // B5

      // ---- flush every 32 steps ----
      if (tt == 31) {
        const int n = tid >> 1;
        const int seg = tid & 1;
        float* op = out + ((size_t)r * N + n) * 1024 + (t - 31) + seg * 16;
        #pragma unroll
        for (int i = 0; i < 4; ++i) {
          float4 v;
          v.x = out_t[seg * 16 + i * 4 + 0][n];
          v.y = out_t[seg * 16 + i * 4 + 1][n];
          v.z = out_t[seg * 16 + i * 4 + 2][n];
          v.w = out_t[seg * 16 + i * 4 + 3][n];
          *(float4*)(op + i * 4) = v;
        }
      }
    }
  }
}

extern "C" void kernel_launch(void* const* d_in, const int* in_sizes, int n_in,
                              void* d_out, int out_size, void* d_ws, size_t ws_size,
                              hipStream_t stream) {
  const float* xs    = (const float*)d_in[0];
  const float* h0    = (const float*)d_in[1];
  const float* gamma = (const float*)d_in[2];
  const float* beta  = (const float*)d_in[3];
  const float* W1    = (const float*)d_in[4];
  const float* lnh_w = (const float*)d_in[5];
  const float* lnh_b = (const float*)d_in[6];
  const float* W2    = (const float*)d_in[7];
  const float* lnx_w = (const float*)d_in[8];
  const float* lnx_b = (const float*)d_in[9];
  float* out = (float*)d_out;

  u16* W1p = (u16*)d_ws;                    // 1 MB
  u16* W2p = W1p + (size_t)1024 * 512;      // 0.5 MB

  prep_weights<<<(65536 + 255) / 256, 256, 0, stream>>>(W1, W2, W1p, W2p);
  rnn_kernel<<<64, 1024, 0, stream>>>(xs, h0, gamma, beta, W1p,
                                      lnh_w, lnh_b, W2p, lnx_w, lnx_b, out);
}

// Round 9
// 40019.785 us; speedup vs baseline: 1.9423x; 1.0005x over previous
//
#include <hip/hip_runtime.h>

#define EPSF 1e-5f

typedef unsigned short u16;
typedef unsigned int u32;

__device__ __forceinline__ u16 f2bf(float f) {
  u32 u = __float_as_uint(f);
  u += 0x7fffu + ((u >> 16) & 1u);   // RNE
  return (u16)(u >> 16);
}
__device__ __forceinline__ u32 packbf(float lo, float hi) {
  return (u32)f2bf(lo) | ((u32)f2bf(hi) << 16);
}

#if __has_builtin(__builtin_amdgcn_fdot2_f32_bf16)
typedef __attribute__((ext_vector_type(2))) __bf16 bf16x2;
__device__ __forceinline__ float dot2bf(u32 w, u32 h, float acc) {
  union { u32 u; bf16x2 v; } a, b; a.u = w; b.u = h;
  return __builtin_amdgcn_fdot2_f32_bf16(a.v, b.v, acc, false);
}
#else
__device__ __forceinline__ float dot2bf(u32 w, u32 h, float acc) {
  float r = fmaf(__uint_as_float(w << 16), __uint_as_float(h << 16), acc);
  return fmaf(__uint_as_float(w & 0xffff0000u), __uint_as_float(h & 0xffff0000u), r);
}
#endif

// W1p: u16 idx (kk*1024 + j)*8 + r = bf16(W1[j][kk*8+r]), kk 0..63 (lane-coalesced 16B)
// W2p: u16 idx (kk*512  + n)*8 + r = bf16(W2[n][kk*8+r]), kk 0..63
__global__ void prep_weights(const float* __restrict__ W1, const float* __restrict__ W2,
                             u16* __restrict__ W1p, u16* __restrict__ W2p) {
  int i = blockIdx.x * blockDim.x + threadIdx.x;
  if (i < 1024 * 64) {
    int j = i >> 6, kk = i & 63;
    const float* src = W1 + (size_t)j * 512 + kk * 8;
    u16* dst = W1p + ((size_t)(kk * 1024 + j)) * 8;
    #pragma unroll
    for (int r = 0; r < 8; ++r) dst[r] = f2bf(src[r]);
  }
  if (i < 512 * 64) {
    int n = i >> 6, kk = i & 63;
    const float* src = W2 + (size_t)n * 512 + kk * 8;
    u16* dst = W2p + ((size_t)(kk * 512 + n)) * 8;
    #pragma unroll
    for (int r = 0; r < 8; ++r) dst[r] = f2bf(src[r]);
  }
}

// 64 blocks (one per batch row) x 1024 threads (16 waves).
// amdgpu_waves_per_eu(4,4): exactly 16 waves/CU -> 1 block/CU -> 128-VGPR budget,
// overriding the allocator's 2-blocks/CU heuristic (rounds 4/6/7/8 all spilled on it).
// mm1: thread tid owns output j = tid. mm2: n = tid&511, k-half = tid>>9.
__global__ __attribute__((amdgpu_flat_work_group_size(1024, 1024), amdgpu_waves_per_eu(4, 4)))
void rnn_kernel(const float* __restrict__ xs, const float* __restrict__ h0,
                const float* __restrict__ gamma, const float* __restrict__ beta,
                const u16* __restrict__ W1p,
                const float* __restrict__ lnh_w, const float* __restrict__ lnh_b,
                const u16* __restrict__ W2p,
                const float* __restrict__ lnx_w, const float* __restrict__ lnx_b,
                float* __restrict__ out) {
  const int r = blockIdx.x;
  const int tid = threadIdx.x;
  const int w = tid >> 6, lane = tid & 63;
  const int N = 512;

  __shared__ u32 hb2[256];
  __shared__ u32 xb2[256];
  __shared__ float hg_s[512];
  __shared__ float p2[1024];
  __shared__ float red_s[16], red_q[16];
  __shared__ __align__(16) float out_t[32][512];   // 64 KB

  // per-thread params
  const float w1w = lnh_w[tid], w1b = lnh_b[tid];
  float g0 = 0, g1 = 0, g2 = 0, b0 = 0, b1 = 0, b2 = 0, w2w = 0, w2b = 0;
  float h_v = 0.f, x_v = 0.f, il = 0.f;
  if (tid < N) {
    g0 = gamma[0 * N + tid]; g1 = gamma[1 * N + tid]; g2 = gamma[2 * N + tid];
    b0 = beta[0 * N + tid];  b1 = beta[1 * N + tid];  b2 = beta[2 * N + tid];
    w2w = lnx_w[tid]; w2b = lnx_b[tid];
    h_v = h0[(size_t)r * N + tid];
    float hnb = __shfl_down(h_v, 1);
    if (!(tid & 1)) hb2[tid >> 1] = packbf(h_v, hnb);
  }
  const float* xs_b = xs + (size_t)r * 3 * N * 1024;
  const uint4* wp1 = ((const uint4*)W1p) + tid;          // elem kk at wp1[kk*1024]
  const int n2 = tid & 511, half = tid >> 9;
  const uint4* wp2 = ((const uint4*)W2p) + n2 + (size_t)half * 32 * 512;  // local kk at wp2[kk*512]
  __syncthreads();

#define M1L(D, g)                                              \
  _Pragma("unroll") for (int u = 0; u < 4; ++u) {              \
    D[u] = wp1[((g) * 4 + u) * 1024];                          \
  }
#define M1C(S, g)                                              \
  _Pragma("unroll") for (int u = 0; u < 4; ++u) {              \
    uint4 h4 = hp4[(g) * 4 + u];                               \
    a0 = dot2bf(S[u].x, h4.x, a0); a1 = dot2bf(S[u].y, h4.y, a1); \
    a2 = dot2bf(S[u].z, h4.z, a2); a3 = dot2bf(S[u].w, h4.w, a3); \
  }
#define M2L(D, g)                                              \
  _Pragma("unroll") for (int u = 0; u < 4; ++u) {              \
    D[u] = wp2[((g) * 4 + u) * 512];                           \
  }
#define M2C(S, g)                                              \
  _Pragma("unroll") for (int u = 0; u < 4; ++u) {              \
    uint4 x4 = xp4[(g) * 4 + u];                               \
    a0 = dot2bf(S[u].x, x4.x, a0); a1 = dot2bf(S[u].y, x4.y, a1); \
    a2 = dot2bf(S[u].z, x4.z, a2); a3 = dot2bf(S[u].w, x4.w, a3); \
  }

  for (int t0 = 0; t0 < 1024; t0 += 4) {
    float4 xr0, xr1, xr2;
    if (tid < N) {
      xr0 = *(const float4*)(xs_b + (size_t)(0 * N + tid) * 1024 + t0);
      xr1 = *(const float4*)(xs_b + (size_t)(1 * N + tid) * 1024 + t0);
      xr2 = *(const float4*)(xs_b + (size_t)(2 * N + tid) * 1024 + t0);
    }
    #pragma unroll
    for (int q = 0; q < 4; ++q) {
      const int t = t0 + q;
      const int tt = t & 31;

      // ---- in_layer (regs) ----
      if (tid < N) {
        float s0 = 1.f / (1.f + __expf(-(g0 * h_v + b0)));
        float s1 = 1.f / (1.f + __expf(-(g1 * h_v + b1)));
        float s2 = 1.f / (1.f + __expf(-(g2 * h_v + b2)));
        float x0 = (q == 0) ? xr0.x : (q == 1) ? xr0.y : (q == 2) ? xr0.z : xr0.w;
        float x1 = (q == 0) ? xr1.x : (q == 1) ? xr1.y : (q == 2) ? xr1.z : xr1.w;
        float x2 = (q == 0) ? xr2.x : (q == 1) ? xr2.y : (q == 2) ? xr2.z : xr2.w;
        il = fmaxf(s0 * x0 + s1 * x1 + s2 * x2, 0.f);
      }

      // ---- mm1: j=tid, depth-4 ping-pong over 16 groups ----
      float acc;
      {
        const uint4* hp4 = (const uint4*)hb2;      // wave-uniform broadcast
        uint4 A[4], B[4];
        float a0 = 0, a1 = 0, a2 = 0, a3 = 0;
        M1L(A, 0);
        M1L(B, 1);  M1C(A, 0);
        M1L(A, 2);  M1C(B, 1);
        M1L(B, 3);  M1C(A, 2);
        M1L(A, 4);  M1C(B, 3);
        M1L(B, 5);  M1C(A, 4);
        M1L(A, 6);  M1C(B, 5);
        M1L(B, 7);  M1C(A, 6);
        M1L(A, 8);  M1C(B, 7);
        M1L(B, 9);  M1C(A, 8);
        M1L(A, 10); M1C(B, 9);
        M1L(B, 11); M1C(A, 10);
        M1L(A, 12); M1C(B, 11);
        M1L(B, 13); M1C(A, 12);
        M1L(A, 14); M1C(B, 13);
        M1L(B, 15); M1C(A, 14);
        M1C(B, 15);
        acc = (a0 + a1) + (a2 + a3);
      }

      // ---- LN1 stats over 1024 ----
      {
        float s = acc, qq = acc * acc;
        #pragma unroll
        for (int off = 32; off > 0; off >>= 1) {
          s += __shfl_down(s, off); qq += __shfl_down(qq, off);
        }
        if (lane == 0) { red_s[w] = s; red_q[w] = qq; }
      }
      __syncthreads();                                   // B1
      float mu1, rinv1;
      {
        float s = red_s[tid & 15], qq = red_q[tid & 15];
        #pragma unroll
        for (int off = 8; off > 0; off >>= 1) {
          s += __shfl_xor(s, off); qq += __shfl_xor(qq, off);
        }
        mu1 = s * (1.f / 1024.f);
        rinv1 = rsqrtf(qq * (1.f / 1024.f) - mu1 * mu1 + EPSF);
      }

      // ---- LN1 apply ----
      {
        float hh = (acc - mu1) * rinv1 * w1w + w1b;
        if (tid < N) {
          x_v = fmaxf(il + hh, 0.f);
          float xnb = __shfl_down(x_v, 1);
          if (!(tid & 1)) xb2[tid >> 1] = packbf(x_v, xnb);
        } else {
          hg_s[tid - N] = hh;
        }
      }
      __syncthreads();                                   // B2

      // ---- mm2: n=tid&511, k-half split, depth-4 ping-pong over 8 groups ----
      {
        const uint4* xp4 = ((const uint4*)xb2) + half * 32;
        uint4 A[4], B[4];
        float a0 = 0, a1 = 0, a2 = 0, a3 = 0;
        M2L(A, 0);
        M2L(B, 1); M2C(A, 0);
        M2L(A, 2); M2C(B, 1);
        M2L(B, 3); M2C(A, 2);
        M2L(A, 4); M2C(B, 3);
        M2L(B, 5); M2C(A, 4);
        M2L(A, 6); M2C(B, 5);
        M2L(B, 7); M2C(A, 6);
        M2C(B, 7);
        p2[tid] = (a0 + a1) + (a2 + a3);
      }
      __syncthreads();                                   // B3

      // ---- LN2 stats over 512 ----
      float accf = 0.f;
      {
        float s = 0.f, qq = 0.f;
        if (tid < N) {
          accf = p2[tid] + p2[tid + 512];
          s = accf; qq = accf * accf;
        }
        #pragma unroll
        for (int off = 32; off > 0; off >>= 1) {
          s += __shfl_down(s, off); qq += __shfl_down(qq, off);
        }
        if (lane == 0) { red_s[w] = s; red_q[w] = qq; }
      }
      __syncthreads();                                   // B4
      {
        float s = red_s[tid & 15], qq = red_q[tid & 15];
        #pragma unroll
        for (int off = 8; off > 0; off >>= 1) {
          s += __shfl_xor(s, off); qq += __shfl_xor(qq, off);
        }
        float mu2 = s * (1.f / 512.f);
        float rinv2 = rsqrtf(qq * (1.f / 512.f) - mu2 * mu2 + EPSF);

        // ---- gate + state update ----
        if (tid < N) {
          float y = (accf - mu2) * rinv2 * w2w + w2b;
          float gg = 1.f / (1.f + __expf(-(y + hg_s[tid])));
          float hn = h_v + gg * (x_v - h_v);
          out_t[tt][tid] = hn;
          h_v = hn;
          float hnb = __shfl_down(hn, 1);
          if (!(tid & 1)) hb2[tid >> 1] = packbf(hn, hnb);
        }
      }
      __syncthreads();                                   // B5

      // ---- flush every 32 steps ----
      if (tt == 31) {
        const int n = tid >> 1;
        const int seg = tid & 1;
        float* op = out + ((size_t)r * N + n) * 1024 + (t - 31) + seg * 16;
        #pragma unroll
        for (int i = 0; i < 4; ++i) {
          float4 v;
          v.x = out_t[seg * 16 + i * 4 + 0][n];
          v.y = out_t[seg * 16 + i * 4 + 1][n];
          v.z = out_t[seg * 16 + i * 4 + 2][n];
          v.w = out_t[seg * 16 + i * 4 + 3][n];
          *(float4*)(op + i * 4) = v;
        }
      }
    }
  }
}

extern "C" void kernel_launch(void* const* d_in, const int* in_sizes, int n_in,
                              void* d_out, int out_size, void* d_ws, size_t ws_size,
                              hipStream_t stream) {
  const float* xs    = (const float*)d_in[0];
  const float* h0    = (const float*)d_in[1];
  const float* gamma = (const float*)d_in[2];
  const float* beta  = (const float*)d_in[3];
  const float* W1    = (const float*)d_in[4];
  const float* lnh_w = (const float*)d_in[5];
  const float* lnh_b = (const float*)d_in[6];
  const float* W2    = (const float*)d_in[7];
  const float* lnx_w = (const float*)d_in[8];
  const float* lnx_b = (const float*)d_in[9];
  float* out = (float*)d_out;

  u16* W1p = (u16*)d_ws;                    // 1 MB
  u16* W2p = W1p + (size_t)1024 * 512;      // 0.5 MB

  prep_weights<<<(65536 + 255) / 256, 256, 0, stream>>>(W1, W2, W1p, W2p);
  rnn_kernel<<<64, 1024, 0, stream>>>(xs, h0, gamma, beta, W1p,
                                      lnh_w, lnh_b, W2p, lnx_w, lnx_b, out);
}